// Round 1
// baseline (242.810 us; speedup 1.0000x reference)
//
#include <hip/hip_runtime.h>
#include <hip/hip_bf16.h>

// R7: attn pipeline + softmax VALU diet on top of R6.
//  - k-loop software pipeline: prefetch tile kt+1 into regs during compute of kt
//    (VMEM latency hidden under S^T/softmax/PV instead of under a barrier).
//  - Q pre-scaled by 0.125*log2e -> bare v_exp_f32 (exp2), no per-elem mul.
//  - mask applied as sign-extended bfe (0/-1) AND exp result: 2 VALU/elem,
//    bit-identical to the old cndmask select (exp2 underflow/AND both give +0).
// prep_kernel / proj_kernel unchanged from R6.

typedef __bf16 bf16;
typedef bf16 bf16x8 __attribute__((ext_vector_type(8)));
typedef bf16 bf16x4 __attribute__((ext_vector_type(4)));
typedef float floatx4 __attribute__((ext_vector_type(4)));
typedef unsigned short ushort8 __attribute__((ext_vector_type(8)));
typedef unsigned long long u64;

#define MFMA32(A, B, C) __builtin_amdgcn_mfma_f32_16x16x32_bf16((A), (B), (C), 0, 0, 0)

namespace {
constexpr int S   = 512;
constexpr int H   = 16;
constexpr int Dh  = 64;
constexpr int D   = 1024;
constexpr int LDT = 72;                          // padded LDS row stride (bf16)
constexpr size_t QN = (size_t)16 * S * H * Dh;   // 8,388,608
constexpr size_t WN = (size_t)D * D;             // 1,048,576
}

__device__ __forceinline__ float fexp2(float x) {
#if defined(__HIP_DEVICE_COMPILE__) && __has_builtin(__builtin_amdgcn_exp2f)
    return __builtin_amdgcn_exp2f(x);
#else
    return exp2f(x);
#endif
}

__device__ __forceinline__ int sbfe1(unsigned bits, int bit) {
#if defined(__HIP_DEVICE_COMPILE__) && __has_builtin(__builtin_amdgcn_sbfe)
    return __builtin_amdgcn_sbfe((int)bits, (unsigned)bit, 1u);
#else
    return ((int)(bits << (31 - bit))) >> 31;    // compiler folds to v_bfe_i32
#endif
}

// Fused prep: [0,4096) K f32->bf16 | [4096,6144) V transpose | [6144,6400) W
// transpose | [6400,10496) mask bit-pack.
__global__ __launch_bounds__(256)
void prep_kernel(const float* __restrict__ Kf, const float* __restrict__ Vf,
                 const float* __restrict__ Wf, const int* __restrict__ Mg,
                 bf16* __restrict__ Kc, bf16* __restrict__ Vt,
                 bf16* __restrict__ Wt, u64* __restrict__ MB)
{
    __shared__ bf16 Ts[64 * LDT];
    const int blk = blockIdx.x, tid = threadIdx.x;

    if (blk < 4096) {                       // ---- K convert ----
        const int i = blk * 256 + tid;
        const float* fs = Kf + (size_t)i * 8;
        bf16x8 v;
#pragma unroll
        for (int j = 0; j < 8; ++j) v[j] = (bf16)fs[j];
        *(bf16x8*)(Kc + (size_t)i * 8) = v;
    } else if (blk < 6144) {                // ---- V [b][s][h][d] -> [(bh)][d][s] ----
        const int bk2 = blk - 4096;
        const int bh  = bk2 >> 3, st = bk2 & 7;
        const int b   = bh >> 4, h = bh & 15;
        const int r   = tid >> 2, c = (tid & 3) * 16;
        const float* src = Vf + ((size_t)((b * S + st * 64 + r) * H + h)) * Dh + c;
#pragma unroll
        for (int i = 0; i < 16; ++i)
            Ts[(c + i) * LDT + r] = (bf16)src[i];
        __syncthreads();
        bf16* dst = Vt + ((size_t)bh * 64 + r) * S + st * 64 + c;
        *(ushort8*)dst       = *(const ushort8*)&Ts[r * LDT + c];
        *(ushort8*)(dst + 8) = *(const ushort8*)&Ts[r * LDT + c + 8];
    } else if (blk < 6400) {                // ---- W [k][n] -> [n][k] ----
        const int bk2 = blk - 6144;
        const int nb  = bk2 & 15, kb = bk2 >> 4;
        const int r   = tid >> 2, c = (tid & 3) * 16;
        const float* src = Wf + (size_t)(kb * 64 + r) * D + nb * 64 + c;
#pragma unroll
        for (int i = 0; i < 16; ++i)
            Ts[(c + i) * LDT + r] = (bf16)src[i];
        __syncthreads();
        bf16* dst = Wt + (size_t)(nb * 64 + r) * D + kb * 64 + c;
        *(ushort8*)dst       = *(const ushort8*)&Ts[r * LDT + c];
        *(ushort8*)(dst + 8) = *(const ushort8*)&Ts[r * LDT + c + 8];
    } else {                                // ---- mask -> u64 bitmask ----
        const int bk2  = blk - 6400;
        const int lane = tid & 63;
        const int idx4 = bk2 * 4 + (tid >> 6);      // [0, 16384)
        const int row  = idx4 >> 1;
        const int half = idx4 & 1;
#pragma unroll
        for (int r = 0; r < 4; ++r) {
            int mv = Mg[(size_t)row * 512 + half * 256 + r * 64 + lane];
            u64 bm = __ballot(mv != 0);
            if (lane == 0) MB[(size_t)row * 8 + half * 4 + r] = bm;
        }
    }
}

// One workgroup = one (b, h, 64-row q-tile). 4 waves, 16 q each (q = qw + l15).
__global__ __launch_bounds__(256, 4)
void attn_kernel(const float* __restrict__ Qg, const bf16* __restrict__ Kc,
                 const bf16* __restrict__ Vtg, const u64* __restrict__ MB,
                 bf16* __restrict__ heads)
{
    __shared__ bf16 Ks[64 * LDT];                 // rows PERMUTED: row r = k sigma(r)
    __shared__ bf16 Vt[64 * LDT];                 // [d][s-in-tile], natural order

    const int tid  = threadIdx.x;
    const int lane = tid & 63;
    const int wave = tid >> 6;
    const int l15  = lane & 15;
    const int quad = lane >> 4;

    const int blk = blockIdx.x;                   // ((b*8)+qt)*16 + h
    const int h   = blk & 15;
    const int qt  = (blk >> 4) & 7;
    const int b   = blk >> 7;
    const int qw  = qt * 64 + wave * 16;          // wave's q base; q = qw + l15

    // ---- Q B-frags direct from global: Q * 0.125 * log2(e) so scores are in
    // log2 domain and exp is a single v_exp_f32 ----
    constexpr float QSCL = 0.125f * 1.44269504088896340736f;
    bf16x8 aq0, aq1;
    {
        const float* qb = Qg + ((size_t)((b * S + qw + l15) * H + h)) * Dh + quad * 8;
        floatx4 f0 = *(const floatx4*)qb;
        floatx4 f1 = *(const floatx4*)(qb + 4);
        floatx4 f2 = *(const floatx4*)(qb + 32);
        floatx4 f3 = *(const floatx4*)(qb + 36);
#pragma unroll
        for (int j = 0; j < 4; ++j) {
            aq0[j]     = (bf16)(f0[j] * QSCL);
            aq0[j + 4] = (bf16)(f1[j] * QSCL);
            aq1[j]     = (bf16)(f2[j] * QSCL);
            aq1[j + 4] = (bf16)(f3[j] * QSCL);
        }
    }

    float rsum = 0.f;
    floatx4 O[4];                                 // O^T[d = mt*16+quad*4+reg][q = l15]
#pragma unroll
    for (int i = 0; i < 4; ++i) O[i] = floatx4{0.f, 0.f, 0.f, 0.f};

    const u64* mbrow = MB + ((size_t)b * S + qw + l15) * 8;   // per-lane q row
    const bf16* vplane = Vtg + (size_t)(b * 16 + h) * 64 * S;

    const int sr = tid >> 2, sc_ = (tid & 3) * 16;            // 64x64 staging
    // sigma(r): staging row r holds global k-slot kperm so that S^T C-tiles
    // land P^T in K=32 B-operand order (lane quad -> k = quad*8 + 0..7).
    const int kperm = ((sr >> 5) << 5) | (((sr & 15) >> 2) << 3)
                    | (((sr >> 4) & 1) << 2) | (sr & 3);

    const bf16* ksrc0 = Kc + ((size_t)((b * S + kperm) * H + h)) * Dh + sc_;
    const bf16* vsrc0 = vplane + (size_t)sr * S + sc_;

    // ---- prologue: prefetch tile 0 into registers ----
    ushort8 k0 = *(const ushort8*)ksrc0;
    ushort8 k1 = *(const ushort8*)(ksrc0 + 8);
    ushort8 v0 = *(const ushort8*)vsrc0;
    ushort8 v1 = *(const ushort8*)(vsrc0 + 8);
    u64 m64 = mbrow[0];

    for (int kt = 0; kt < 8; ++kt) {
        __syncthreads();                          // prev tile's LDS reads done
        *(ushort8*)&Ks[sr * LDT + sc_]     = k0;
        *(ushort8*)&Ks[sr * LDT + sc_ + 8] = k1;
        *(ushort8*)&Vt[sr * LDT + sc_]     = v0;
        *(ushort8*)&Vt[sr * LDT + sc_ + 8] = v1;
        const u64 mcur = m64;
        __syncthreads();

        // ---- prefetch tile kt+1; latency hides under the compute below ----
        if (kt < 7) {
            const bf16* ks = ksrc0 + (size_t)(kt + 1) * 64 * H * Dh;
            const bf16* vs = vsrc0 + (kt + 1) * 64;
            k0 = *(const ushort8*)ks;
            k1 = *(const ushort8*)(ks + 8);
            v0 = *(const ushort8*)vs;
            v1 = *(const ushort8*)(vs + 8);
            m64 = mbrow[kt + 1];
        }

        // per-tile mask words for this lane's q-row, shifted by quad's k-base
        const unsigned qlo = (unsigned)(mcur >> (quad * 8));        // k bits [q8, q8+32)
        const unsigned qhi = (unsigned)(mcur >> (quad * 8 + 32));   // k bits [q8+32, ..)

        // ---- S^T: A = permuted K rows, B = Q. C row (quad,reg) of tile mt
        // holds k = block*32 + quad*8 + tile*4 + reg (block=mt>>1, tile=mt&1). ----
        bf16x8 pB[2];                             // packed P^T B-operands per 32-k block
#pragma unroll
        for (int mt = 0; mt < 4; ++mt) {
            bf16x8 ak0 = *(const bf16x8*)&Ks[(mt * 16 + l15) * LDT + quad * 8];
            bf16x8 ak1 = *(const bf16x8*)&Ks[(mt * 16 + l15) * LDT + quad * 8 + 32];
            floatx4 acc = floatx4{0.f, 0.f, 0.f, 0.f};
            acc = MFMA32(ak0, aq0, acc);
            acc = MFMA32(ak1, aq1, acc);
            const int block = mt >> 1, tile = mt & 1;
            const unsigned bits = (block ? qhi : qlo) >> (tile * 4);
#pragma unroll
            for (int reg = 0; reg < 4; ++reg) {
                float e = fexp2(acc[reg]);                  // v_exp_f32
                int sx = sbfe1(bits, reg);                  // 0 or -1
                float p = __uint_as_float(__float_as_uint(e) & (unsigned)sx);
                rsum += p;
                pB[block][tile * 4 + reg] = (bf16)p;
            }
        }

        // ---- O^T += V^T · P^T : standard MFMA32, A = Vt rows (natural order) ----
#pragma unroll
        for (int block = 0; block < 2; ++block) {
#pragma unroll
            for (int mt = 0; mt < 4; ++mt) {      // d-tile
                bf16x8 av = *(const bf16x8*)&Vt[(mt * 16 + l15) * LDT + block * 32 + quad * 8];
                O[mt] = MFMA32(av, pB[block], O[mt]);
            }
        }
    }

    // ---- reduce row sums across quads (each lane column q = l15) ----
    rsum += __shfl_xor(rsum, 16, 64);
    rsum += __shfl_xor(rsum, 32, 64);
    const float inv = (rsum > 0.f) ? (1.f / rsum) : 0.f;

    // ---- epilogue: O^T[d][q] -> heads[b][q][h][d], 8B vector stores ----
    bf16* hrow = heads + ((size_t)((b * S + qw + l15) * H + h)) * Dh;
#pragma unroll
    for (int mt = 0; mt < 4; ++mt) {
        bf16x4 h4;
#pragma unroll
        for (int reg = 0; reg < 4; ++reg) h4[reg] = (bf16)(O[mt][reg] * inv);
        *(bf16x4*)&hrow[mt * 16 + quad * 4] = h4;
    }
}

// Projection: heads (8192x1024) @ Wt^T, 128x128 block tile, 4 waves x 64x64.
__global__ __launch_bounds__(256)
void proj_kernel(const bf16* __restrict__ A, const bf16* __restrict__ Wt,
                 float* __restrict__ out)
{
    __shared__ bf16 As[128 * LDT];
    __shared__ bf16 Ws[128 * LDT];

    const int tid  = threadIdx.x;
    const int lane = tid & 63;
    const int wave = tid >> 6;
    const int l15  = lane & 15;
    const int quad = lane >> 4;

    const int nb = blockIdx.x & 7;
    const int mb = blockIdx.x >> 3;
    const int mbase = mb * 128, nbase = nb * 128;
    const int wm = (wave & 1) * 64, wn = (wave >> 1) * 64;

    const int pr = tid >> 1, pc = (tid & 1) * 32;

    floatx4 O[4][4];
#pragma unroll
    for (int mt = 0; mt < 4; ++mt)
#pragma unroll
        for (int nt = 0; nt < 4; ++nt) O[mt][nt] = floatx4{0.f, 0.f, 0.f, 0.f};

    for (int kt = 0; kt < 16; ++kt) {
        const int kb = kt * 64;
        const bf16* asrc = A  + (size_t)(mbase + pr) * D + kb + pc;
        const bf16* wsrc = Wt + (size_t)(nbase + pr) * D + kb + pc;
        ushort8 a0 = *(const ushort8*)asrc;
        ushort8 a1 = *(const ushort8*)(asrc + 8);
        ushort8 a2 = *(const ushort8*)(asrc + 16);
        ushort8 a3 = *(const ushort8*)(asrc + 24);
        ushort8 w0 = *(const ushort8*)wsrc;
        ushort8 w1 = *(const ushort8*)(wsrc + 8);
        ushort8 w2 = *(const ushort8*)(wsrc + 16);
        ushort8 w3 = *(const ushort8*)(wsrc + 24);

        __syncthreads();
        *(ushort8*)&As[pr * LDT + pc]      = a0;
        *(ushort8*)&As[pr * LDT + pc + 8]  = a1;
        *(ushort8*)&As[pr * LDT + pc + 16] = a2;
        *(ushort8*)&As[pr * LDT + pc + 24] = a3;
        *(ushort8*)&Ws[pr * LDT + pc]      = w0;
        *(ushort8*)&Ws[pr * LDT + pc + 8]  = w1;
        *(ushort8*)&Ws[pr * LDT + pc + 16] = w2;
        *(ushort8*)&Ws[pr * LDT + pc + 24] = w3;
        __syncthreads();

        bf16x8 fa[4][2];
#pragma unroll
        for (int mt = 0; mt < 4; ++mt) {
            fa[mt][0] = *(const bf16x8*)&As[(wm + mt * 16 + l15) * LDT + quad * 8];
            fa[mt][1] = *(const bf16x8*)&As[(wm + mt * 16 + l15) * LDT + quad * 8 + 32];
        }
#pragma unroll
        for (int nt = 0; nt < 4; ++nt) {
            bf16x8 fb0 = *(const bf16x8*)&Ws[(wn + nt * 16 + l15) * LDT + quad * 8];
            bf16x8 fb1 = *(const bf16x8*)&Ws[(wn + nt * 16 + l15) * LDT + quad * 8 + 32];
#pragma unroll
            for (int mt = 0; mt < 4; ++mt) {
                O[mt][nt] = MFMA32(fa[mt][0], fb0, O[mt][nt]);
                O[mt][nt] = MFMA32(fa[mt][1], fb1, O[mt][nt]);
            }
        }
    }

#pragma unroll
    for (int mt = 0; mt < 4; ++mt) {
#pragma unroll
        for (int nt = 0; nt < 4; ++nt) {
#pragma unroll
            for (int reg = 0; reg < 4; ++reg) {
                const int m = mbase + wm + mt * 16 + quad * 4 + reg;
                const int n = nbase + wn + nt * 16 + l15;
                out[(size_t)m * D + n] = O[mt][nt][reg];
            }
        }
    }
}

extern "C" void kernel_launch(void* const* d_in, const int* in_sizes, int n_in,
                              void* d_out, int out_size, void* d_ws, size_t ws_size,
                              hipStream_t stream)
{
    const float* pre_q = (const float*)d_in[0];
    const float* pre_v = (const float*)d_in[1];
    const float* pre_k = (const float*)d_in[2];
    const int*   mask  = (const int*)d_in[3];
    const float* Wg    = (const float*)d_in[4];
    float* out = (float*)d_out;

    bf16* Kc    = (bf16*)d_ws;
    bf16* Vt    = Kc + QN;
    bf16* Wt    = Vt + QN;
    bf16* heads = Wt + WN;
    u64*  MB    = (u64*)(heads + QN);

    prep_kernel<<<10496, 256, 0, stream>>>(pre_k, pre_v, Wg, mask, Kc, Vt, Wt, MB);
    attn_kernel<<<2048, 256, 0, stream>>>(pre_q, Kc, Vt, MB, heads);
    proj_kernel<<<512, 256, 0, stream>>>(heads, Wt, out);
}

// Round 3
// 215.069 us; speedup vs baseline: 1.1290x; 1.1290x over previous
//
#include <hip/hip_runtime.h>
#include <hip/hip_bf16.h>

// R8 (resubmit; round-2 bench was an infra failure, no signal).
// R6 structure (no register prefetch -- R7's pipeline spilled to scratch,
// WRITE_SIZE 16->100MB) + the softmax VALU diet that was riding along in R7:
//  - Q pre-scaled by 0.125*log2e -> score in log2 domain, bare v_exp_f32.
//  - mask via sign-extended bfe (0/-1) AND exp: 2 VALU/elem vs 4-5.
// prep_kernel / proj_kernel unchanged from R6.

typedef __bf16 bf16;
typedef bf16 bf16x8 __attribute__((ext_vector_type(8)));
typedef bf16 bf16x4 __attribute__((ext_vector_type(4)));
typedef float floatx4 __attribute__((ext_vector_type(4)));
typedef unsigned short ushort8 __attribute__((ext_vector_type(8)));
typedef unsigned long long u64;

#define MFMA32(A, B, C) __builtin_amdgcn_mfma_f32_16x16x32_bf16((A), (B), (C), 0, 0, 0)

namespace {
constexpr int S   = 512;
constexpr int H   = 16;
constexpr int Dh  = 64;
constexpr int D   = 1024;
constexpr int LDT = 72;                          // padded LDS row stride (bf16)
constexpr size_t QN = (size_t)16 * S * H * Dh;   // 8,388,608
constexpr size_t WN = (size_t)D * D;             // 1,048,576
}

__device__ __forceinline__ float fexp2(float x) {
#if defined(__HIP_DEVICE_COMPILE__) && __has_builtin(__builtin_amdgcn_exp2f)
    return __builtin_amdgcn_exp2f(x);
#else
    return exp2f(x);
#endif
}

__device__ __forceinline__ int sbfe1(unsigned bits, int bit) {
    return ((int)(bits << (31 - bit))) >> 31;    // folds to v_bfe_i32
}

// Fused prep: [0,4096) K f32->bf16 | [4096,6144) V transpose | [6144,6400) W
// transpose | [6400,10496) mask bit-pack.
__global__ __launch_bounds__(256)
void prep_kernel(const float* __restrict__ Kf, const float* __restrict__ Vf,
                 const float* __restrict__ Wf, const int* __restrict__ Mg,
                 bf16* __restrict__ Kc, bf16* __restrict__ Vt,
                 bf16* __restrict__ Wt, u64* __restrict__ MB)
{
    __shared__ bf16 Ts[64 * LDT];
    const int blk = blockIdx.x, tid = threadIdx.x;

    if (blk < 4096) {                       // ---- K convert ----
        const int i = blk * 256 + tid;
        const float* fs = Kf + (size_t)i * 8;
        bf16x8 v;
#pragma unroll
        for (int j = 0; j < 8; ++j) v[j] = (bf16)fs[j];
        *(bf16x8*)(Kc + (size_t)i * 8) = v;
    } else if (blk < 6144) {                // ---- V [b][s][h][d] -> [(bh)][d][s] ----
        const int bk2 = blk - 4096;
        const int bh  = bk2 >> 3, st = bk2 & 7;
        const int b   = bh >> 4, h = bh & 15;
        const int r   = tid >> 2, c = (tid & 3) * 16;
        const float* src = Vf + ((size_t)((b * S + st * 64 + r) * H + h)) * Dh + c;
#pragma unroll
        for (int i = 0; i < 16; ++i)
            Ts[(c + i) * LDT + r] = (bf16)src[i];
        __syncthreads();
        bf16* dst = Vt + ((size_t)bh * 64 + r) * S + st * 64 + c;
        *(ushort8*)dst       = *(const ushort8*)&Ts[r * LDT + c];
        *(ushort8*)(dst + 8) = *(const ushort8*)&Ts[r * LDT + c + 8];
    } else if (blk < 6400) {                // ---- W [k][n] -> [n][k] ----
        const int bk2 = blk - 6144;
        const int nb  = bk2 & 15, kb = bk2 >> 4;
        const int r   = tid >> 2, c = (tid & 3) * 16;
        const float* src = Wf + (size_t)(kb * 64 + r) * D + nb * 64 + c;
#pragma unroll
        for (int i = 0; i < 16; ++i)
            Ts[(c + i) * LDT + r] = (bf16)src[i];
        __syncthreads();
        bf16* dst = Wt + (size_t)(nb * 64 + r) * D + kb * 64 + c;
        *(ushort8*)dst       = *(const ushort8*)&Ts[r * LDT + c];
        *(ushort8*)(dst + 8) = *(const ushort8*)&Ts[r * LDT + c + 8];
    } else {                                // ---- mask -> u64 bitmask ----
        const int bk2  = blk - 6400;
        const int lane = tid & 63;
        const int idx4 = bk2 * 4 + (tid >> 6);      // [0, 16384)
        const int row  = idx4 >> 1;
        const int half = idx4 & 1;
#pragma unroll
        for (int r = 0; r < 4; ++r) {
            int mv = Mg[(size_t)row * 512 + half * 256 + r * 64 + lane];
            u64 bm = __ballot(mv != 0);
            if (lane == 0) MB[(size_t)row * 8 + half * 4 + r] = bm;
        }
    }
}

// One workgroup = one (b, h, 64-row q-tile). 4 waves, 16 q each (q = qw + l15).
__global__ __launch_bounds__(256, 4)
void attn_kernel(const float* __restrict__ Qg, const bf16* __restrict__ Kc,
                 const bf16* __restrict__ Vtg, const u64* __restrict__ MB,
                 bf16* __restrict__ heads)
{
    __shared__ bf16 Ks[64 * LDT];                 // rows PERMUTED: row r = k sigma(r)
    __shared__ bf16 Vt[64 * LDT];                 // [d][s-in-tile], natural order

    const int tid  = threadIdx.x;
    const int lane = tid & 63;
    const int wave = tid >> 6;
    const int l15  = lane & 15;
    const int quad = lane >> 4;

    const int blk = blockIdx.x;                   // ((b*8)+qt)*16 + h
    const int h   = blk & 15;
    const int qt  = (blk >> 4) & 7;
    const int b   = blk >> 7;
    const int qw  = qt * 64 + wave * 16;          // wave's q base; q = qw + l15

    // ---- Q B-frags direct from global: Q * 0.125 * log2(e) so scores are in
    // log2 domain and exp is a single v_exp_f32 ----
    constexpr float QSCL = 0.125f * 1.44269504088896340736f;
    bf16x8 aq0, aq1;
    {
        const float* qb = Qg + ((size_t)((b * S + qw + l15) * H + h)) * Dh + quad * 8;
        floatx4 f0 = *(const floatx4*)qb;
        floatx4 f1 = *(const floatx4*)(qb + 4);
        floatx4 f2 = *(const floatx4*)(qb + 32);
        floatx4 f3 = *(const floatx4*)(qb + 36);
#pragma unroll
        for (int j = 0; j < 4; ++j) {
            aq0[j]     = (bf16)(f0[j] * QSCL);
            aq0[j + 4] = (bf16)(f1[j] * QSCL);
            aq1[j]     = (bf16)(f2[j] * QSCL);
            aq1[j + 4] = (bf16)(f3[j] * QSCL);
        }
    }

    float rsum = 0.f;
    floatx4 O[4];                                 // O^T[d = mt*16+quad*4+reg][q = l15]
#pragma unroll
    for (int i = 0; i < 4; ++i) O[i] = floatx4{0.f, 0.f, 0.f, 0.f};

    const u64* mbrow = MB + ((size_t)b * S + qw + l15) * 8;   // per-lane q row
    const bf16* vplane = Vtg + (size_t)(b * 16 + h) * 64 * S;

    const int sr = tid >> 2, sc_ = (tid & 3) * 16;            // 64x64 staging
    // sigma(r): staging row r holds global k-slot kperm so that S^T C-tiles
    // land P^T in K=32 B-operand order (lane quad -> k = quad*8 + 0..7).
    const int kperm = ((sr >> 5) << 5) | (((sr & 15) >> 2) << 3)
                    | (((sr >> 4) & 1) << 2) | (sr & 3);

    for (int kt = 0; kt < 8; ++kt) {
        const int kb = kt * 64;
        const bf16* ksrc = Kc + ((size_t)((b * S + kb + kperm) * H + h)) * Dh + sc_;
        const bf16* vsrc = vplane + (size_t)sr * S + kb + sc_;
        ushort8 k0 = *(const ushort8*)ksrc;
        ushort8 k1 = *(const ushort8*)(ksrc + 8);
        ushort8 v0 = *(const ushort8*)vsrc;
        ushort8 v1 = *(const ushort8*)(vsrc + 8);
        u64 m64 = mbrow[kt];                      // bit k of this lane's q row

        __syncthreads();                          // prev tile's LDS reads done
        *(ushort8*)&Ks[sr * LDT + sc_]     = k0;
        *(ushort8*)&Ks[sr * LDT + sc_ + 8] = k1;
        *(ushort8*)&Vt[sr * LDT + sc_]     = v0;
        *(ushort8*)&Vt[sr * LDT + sc_ + 8] = v1;
        __syncthreads();

        // per-tile mask words for this lane's q-row, shifted by quad's k-base
        const unsigned qlo = (unsigned)(m64 >> (quad * 8));        // k bits [q8, ..)
        const unsigned qhi = (unsigned)(m64 >> (quad * 8 + 32));   // k bits [q8+32, ..)

        // ---- S^T: A = permuted K rows, B = Q. C row (quad,reg) of tile mt
        // holds k = block*32 + quad*8 + tile*4 + reg (block=mt>>1, tile=mt&1). ----
        bf16x8 pB[2];                             // packed P^T B-operands per 32-k block
#pragma unroll
        for (int mt = 0; mt < 4; ++mt) {
            bf16x8 ak0 = *(const bf16x8*)&Ks[(mt * 16 + l15) * LDT + quad * 8];
            bf16x8 ak1 = *(const bf16x8*)&Ks[(mt * 16 + l15) * LDT + quad * 8 + 32];
            floatx4 acc = floatx4{0.f, 0.f, 0.f, 0.f};
            acc = MFMA32(ak0, aq0, acc);
            acc = MFMA32(ak1, aq1, acc);
            const int block = mt >> 1, tile = mt & 1;
            const unsigned bits = (block ? qhi : qlo) >> (tile * 4);
#pragma unroll
            for (int reg = 0; reg < 4; ++reg) {
                float e = fexp2(acc[reg]);                  // v_exp_f32
                int sx = sbfe1(bits, reg);                  // 0 or -1
                float p = __uint_as_float(__float_as_uint(e) & (unsigned)sx);
                rsum += p;
                pB[block][tile * 4 + reg] = (bf16)p;
            }
        }

        // ---- O^T += V^T · P^T : standard MFMA32, A = Vt rows (natural order) ----
#pragma unroll
        for (int block = 0; block < 2; ++block) {
#pragma unroll
            for (int mt = 0; mt < 4; ++mt) {      // d-tile
                bf16x8 av = *(const bf16x8*)&Vt[(mt * 16 + l15) * LDT + block * 32 + quad * 8];
                O[mt] = MFMA32(av, pB[block], O[mt]);
            }
        }
    }

    // ---- reduce row sums across quads (each lane column q = l15) ----
    rsum += __shfl_xor(rsum, 16, 64);
    rsum += __shfl_xor(rsum, 32, 64);
    const float inv = (rsum > 0.f) ? (1.f / rsum) : 0.f;

    // ---- epilogue: O^T[d][q] -> heads[b][q][h][d], 8B vector stores ----
    bf16* hrow = heads + ((size_t)((b * S + qw + l15) * H + h)) * Dh;
#pragma unroll
    for (int mt = 0; mt < 4; ++mt) {
        bf16x4 h4;
#pragma unroll
        for (int reg = 0; reg < 4; ++reg) h4[reg] = (bf16)(O[mt][reg] * inv);
        *(bf16x4*)&hrow[mt * 16 + quad * 4] = h4;
    }
}

// Projection: heads (8192x1024) @ Wt^T, 128x128 block tile, 4 waves x 64x64.
__global__ __launch_bounds__(256)
void proj_kernel(const bf16* __restrict__ A, const bf16* __restrict__ Wt,
                 float* __restrict__ out)
{
    __shared__ bf16 As[128 * LDT];
    __shared__ bf16 Ws[128 * LDT];

    const int tid  = threadIdx.x;
    const int lane = tid & 63;
    const int wave = tid >> 6;
    const int l15  = lane & 15;
    const int quad = lane >> 4;

    const int nb = blockIdx.x & 7;
    const int mb = blockIdx.x >> 3;
    const int mbase = mb * 128, nbase = nb * 128;
    const int wm = (wave & 1) * 64, wn = (wave >> 1) * 64;

    const int pr = tid >> 1, pc = (tid & 1) * 32;

    floatx4 O[4][4];
#pragma unroll
    for (int mt = 0; mt < 4; ++mt)
#pragma unroll
        for (int nt = 0; nt < 4; ++nt) O[mt][nt] = floatx4{0.f, 0.f, 0.f, 0.f};

    for (int kt = 0; kt < 16; ++kt) {
        const int kb = kt * 64;
        const bf16* asrc = A  + (size_t)(mbase + pr) * D + kb + pc;
        const bf16* wsrc = Wt + (size_t)(nbase + pr) * D + kb + pc;
        ushort8 a0 = *(const ushort8*)asrc;
        ushort8 a1 = *(const ushort8*)(asrc + 8);
        ushort8 a2 = *(const ushort8*)(asrc + 16);
        ushort8 a3 = *(const ushort8*)(asrc + 24);
        ushort8 w0 = *(const ushort8*)wsrc;
        ushort8 w1 = *(const ushort8*)(wsrc + 8);
        ushort8 w2 = *(const ushort8*)(wsrc + 16);
        ushort8 w3 = *(const ushort8*)(wsrc + 24);

        __syncthreads();
        *(ushort8*)&As[pr * LDT + pc]      = a0;
        *(ushort8*)&As[pr * LDT + pc + 8]  = a1;
        *(ushort8*)&As[pr * LDT + pc + 16] = a2;
        *(ushort8*)&As[pr * LDT + pc + 24] = a3;
        *(ushort8*)&Ws[pr * LDT + pc]      = w0;
        *(ushort8*)&Ws[pr * LDT + pc + 8]  = w1;
        *(ushort8*)&Ws[pr * LDT + pc + 16] = w2;
        *(ushort8*)&Ws[pr * LDT + pc + 24] = w3;
        __syncthreads();

        bf16x8 fa[4][2];
#pragma unroll
        for (int mt = 0; mt < 4; ++mt) {
            fa[mt][0] = *(const bf16x8*)&As[(wm + mt * 16 + l15) * LDT + quad * 8];
            fa[mt][1] = *(const bf16x8*)&As[(wm + mt * 16 + l15) * LDT + quad * 8 + 32];
        }
#pragma unroll
        for (int nt = 0; nt < 4; ++nt) {
            bf16x8 fb0 = *(const bf16x8*)&Ws[(wn + nt * 16 + l15) * LDT + quad * 8];
            bf16x8 fb1 = *(const bf16x8*)&Ws[(wn + nt * 16 + l15) * LDT + quad * 8 + 32];
#pragma unroll
            for (int mt = 0; mt < 4; ++mt) {
                O[mt][nt] = MFMA32(fa[mt][0], fb0, O[mt][nt]);
                O[mt][nt] = MFMA32(fa[mt][1], fb1, O[mt][nt]);
            }
        }
    }

#pragma unroll
    for (int mt = 0; mt < 4; ++mt) {
#pragma unroll
        for (int nt = 0; nt < 4; ++nt) {
#pragma unroll
            for (int reg = 0; reg < 4; ++reg) {
                const int m = mbase + wm + mt * 16 + quad * 4 + reg;
                const int n = nbase + wn + nt * 16 + l15;
                out[(size_t)m * D + n] = O[mt][nt][reg];
            }
        }
    }
}

extern "C" void kernel_launch(void* const* d_in, const int* in_sizes, int n_in,
                              void* d_out, int out_size, void* d_ws, size_t ws_size,
                              hipStream_t stream)
{
    const float* pre_q = (const float*)d_in[0];
    const float* pre_v = (const float*)d_in[1];
    const float* pre_k = (const float*)d_in[2];
    const int*   mask  = (const int*)d_in[3];
    const float* Wg    = (const float*)d_in[4];
    float* out = (float*)d_out;

    bf16* Kc    = (bf16*)d_ws;
    bf16* Vt    = Kc + QN;
    bf16* Wt    = Vt + QN;
    bf16* heads = Wt + WN;
    u64*  MB    = (u64*)(heads + QN);

    prep_kernel<<<10496, 256, 0, stream>>>(pre_k, pre_v, Wg, mask, Kc, Vt, Wt, MB);
    attn_kernel<<<2048, 256, 0, stream>>>(pre_q, Kc, Vt, MB, heads);
    proj_kernel<<<512, 256, 0, stream>>>(heads, Wt, out);
}

// Round 4
// 211.555 us; speedup vs baseline: 1.1477x; 1.0166x over previous
//
#include <hip/hip_runtime.h>
#include <hip/hip_bf16.h>

// R9: attn rewritten on mfma_f32_32x32x16_bf16 -- 32 q-rows per wave (was 16).
// Each wave's LDS K/V-tile reads now serve 2x the q-rows: wave count halves
// (grid 2048->1024, 128 q/block), halving LDS read traffic, bank conflicts,
// barriers, and K/V L2 re-reads. K-rows staged with bits 2<->3 swapped so the
// 32x32 S^T C-layout (row=(reg&3)+8*(reg>>2)+4*half) lands P^T exactly in the
// 32x32x16 B-operand order: pB[s][j] = C[s*8+j], no cross-lane repack.
// Softmax diet from R8 kept (exp2 domain + sbfe mask). prep/proj unchanged.

typedef __bf16 bf16;
typedef bf16 bf16x8 __attribute__((ext_vector_type(8)));
typedef bf16 bf16x4 __attribute__((ext_vector_type(4)));
typedef float floatx4 __attribute__((ext_vector_type(4)));
typedef float floatx16 __attribute__((ext_vector_type(16)));
typedef unsigned short ushort8 __attribute__((ext_vector_type(8)));
typedef unsigned long long u64;

#define MFMA32(A, B, C)  __builtin_amdgcn_mfma_f32_16x16x32_bf16((A), (B), (C), 0, 0, 0)
#define MFMA32x32(A, B, C) __builtin_amdgcn_mfma_f32_32x32x16_bf16((A), (B), (C), 0, 0, 0)

namespace {
constexpr int S   = 512;
constexpr int H   = 16;
constexpr int Dh  = 64;
constexpr int D   = 1024;
constexpr int LDT = 72;                          // padded LDS row stride (bf16)
constexpr size_t QN = (size_t)16 * S * H * Dh;   // 8,388,608
constexpr size_t WN = (size_t)D * D;             // 1,048,576
}

__device__ __forceinline__ float fexp2(float x) {
#if defined(__HIP_DEVICE_COMPILE__) && __has_builtin(__builtin_amdgcn_exp2f)
    return __builtin_amdgcn_exp2f(x);
#else
    return exp2f(x);
#endif
}

__device__ __forceinline__ int sbfe1(unsigned bits, int bit) {
    return ((int)(bits << (31 - bit))) >> 31;    // folds to v_bfe_i32
}

// Fused prep: [0,4096) K f32->bf16 | [4096,6144) V transpose | [6144,6400) W
// transpose | [6400,10496) mask bit-pack.
__global__ __launch_bounds__(256)
void prep_kernel(const float* __restrict__ Kf, const float* __restrict__ Vf,
                 const float* __restrict__ Wf, const int* __restrict__ Mg,
                 bf16* __restrict__ Kc, bf16* __restrict__ Vt,
                 bf16* __restrict__ Wt, u64* __restrict__ MB)
{
    __shared__ bf16 Ts[64 * LDT];
    const int blk = blockIdx.x, tid = threadIdx.x;

    if (blk < 4096) {                       // ---- K convert ----
        const int i = blk * 256 + tid;
        const float* fs = Kf + (size_t)i * 8;
        bf16x8 v;
#pragma unroll
        for (int j = 0; j < 8; ++j) v[j] = (bf16)fs[j];
        *(bf16x8*)(Kc + (size_t)i * 8) = v;
    } else if (blk < 6144) {                // ---- V [b][s][h][d] -> [(bh)][d][s] ----
        const int bk2 = blk - 4096;
        const int bh  = bk2 >> 3, st = bk2 & 7;
        const int b   = bh >> 4, h = bh & 15;
        const int r   = tid >> 2, c = (tid & 3) * 16;
        const float* src = Vf + ((size_t)((b * S + st * 64 + r) * H + h)) * Dh + c;
#pragma unroll
        for (int i = 0; i < 16; ++i)
            Ts[(c + i) * LDT + r] = (bf16)src[i];
        __syncthreads();
        bf16* dst = Vt + ((size_t)bh * 64 + r) * S + st * 64 + c;
        *(ushort8*)dst       = *(const ushort8*)&Ts[r * LDT + c];
        *(ushort8*)(dst + 8) = *(const ushort8*)&Ts[r * LDT + c + 8];
    } else if (blk < 6400) {                // ---- W [k][n] -> [n][k] ----
        const int bk2 = blk - 6144;
        const int nb  = bk2 & 15, kb = bk2 >> 4;
        const int r   = tid >> 2, c = (tid & 3) * 16;
        const float* src = Wf + (size_t)(kb * 64 + r) * D + nb * 64 + c;
#pragma unroll
        for (int i = 0; i < 16; ++i)
            Ts[(c + i) * LDT + r] = (bf16)src[i];
        __syncthreads();
        bf16* dst = Wt + (size_t)(nb * 64 + r) * D + kb * 64 + c;
        *(ushort8*)dst       = *(const ushort8*)&Ts[r * LDT + c];
        *(ushort8*)(dst + 8) = *(const ushort8*)&Ts[r * LDT + c + 8];
    } else {                                // ---- mask -> u64 bitmask ----
        const int bk2  = blk - 6400;
        const int lane = tid & 63;
        const int idx4 = bk2 * 4 + (tid >> 6);      // [0, 16384)
        const int row  = idx4 >> 1;
        const int half = idx4 & 1;
#pragma unroll
        for (int r = 0; r < 4; ++r) {
            int mv = Mg[(size_t)row * 512 + half * 256 + r * 64 + lane];
            u64 bm = __ballot(mv != 0);
            if (lane == 0) MB[(size_t)row * 8 + half * 4 + r] = bm;
        }
    }
}

// One workgroup = one (b, h, 128-row q-tile). 4 waves x 32 q each (q = qw + l31).
// S^T and PV on mfma_f32_32x32x16_bf16; C/D: col=lane&31, row=(reg&3)+8*(reg>>2)+4*half.
__global__ __launch_bounds__(256, 4)
void attn_kernel(const float* __restrict__ Qg, const bf16* __restrict__ Kc,
                 const bf16* __restrict__ Vtg, const u64* __restrict__ MB,
                 bf16* __restrict__ heads)
{
    __shared__ bf16 Ks[64 * LDT];                 // rows PERMUTED: slot r = k-row swap23(r)
    __shared__ bf16 Vt[64 * LDT];                 // [d][s-in-tile], natural order

    const int tid  = threadIdx.x;
    const int lane = tid & 63;
    const int wave = tid >> 6;
    const int l31  = lane & 31;
    const int half = lane >> 5;

    const int blk = blockIdx.x;                   // ((b*4)+qt)*16 + h
    const int h   = blk & 15;
    const int qt  = (blk >> 4) & 3;
    const int b   = blk >> 6;
    const int qw  = qt * 128 + wave * 32;         // wave's q base; q = qw + l31

    // ---- Q B-frags: lane holds Q[qw+l31][ds*16 + half*8 + j] * 0.125*log2e ----
    constexpr float QSCL = 0.125f * 1.44269504088896340736f;
    bf16x8 aq[4];
    {
        const float* qb = Qg + ((size_t)((b * S + qw + l31) * H + h)) * Dh + half * 8;
#pragma unroll
        for (int ds = 0; ds < 4; ++ds) {
            floatx4 f0 = *(const floatx4*)(qb + ds * 16);
            floatx4 f1 = *(const floatx4*)(qb + ds * 16 + 4);
#pragma unroll
            for (int j = 0; j < 4; ++j) {
                aq[ds][j]     = (bf16)(f0[j] * QSCL);
                aq[ds][j + 4] = (bf16)(f1[j] * QSCL);
            }
        }
    }

    float rsum = 0.f;
    floatx16 O[2];                                // O^T[d = dt*32 + crow][q = l31]
#pragma unroll
    for (int dt = 0; dt < 2; ++dt)
#pragma unroll
        for (int i = 0; i < 16; ++i) O[dt][i] = 0.f;

    const u64* mbrow = MB + ((size_t)b * S + qw + l31) * 8;   // per-lane q row
    const bf16* vplane = Vtg + (size_t)(b * 16 + h) * 64 * S;

    const int sr = tid >> 2, sc_ = (tid & 3) * 16;            // 64x64 staging
    // swap bits 2<->3: staging slot r holds global k-row kperm so the S^T
    // C-tile lands P^T in 32x32x16 B-operand order (slot s*8+j <-> C reg s*8+j).
    const int kperm = (sr & 0x33) | ((sr & 4) << 1) | ((sr & 8) >> 1);

    for (int kt = 0; kt < 8; ++kt) {
        const int kb = kt * 64;
        const bf16* ksrc = Kc + ((size_t)((b * S + kb + kperm) * H + h)) * Dh + sc_;
        const bf16* vsrc = vplane + (size_t)sr * S + kb + sc_;
        ushort8 k0 = *(const ushort8*)ksrc;
        ushort8 k1 = *(const ushort8*)(ksrc + 8);
        ushort8 v0 = *(const ushort8*)vsrc;
        ushort8 v1 = *(const ushort8*)(vsrc + 8);
        u64 m64 = mbrow[kt];                      // bit k of this lane's q row

        __syncthreads();                          // prev tile's LDS reads done
        *(ushort8*)&Ks[sr * LDT + sc_]     = k0;
        *(ushort8*)&Ks[sr * LDT + sc_ + 8] = k1;
        *(ushort8*)&Vt[sr * LDT + sc_]     = v0;
        *(ushort8*)&Vt[sr * LDT + sc_ + 8] = v1;
        __syncthreads();

        // ---- S^T per 32-k tile t: A = permuted K rows, B = Q; then softmax.
        // C reg r of tile t holds global k = t*32 + (r>>3)*16 + half*8 + (r&7). ----
        bf16x8 pB[4];                             // P^T B-operands, 16-k slice each
#pragma unroll
        for (int t = 0; t < 2; ++t) {
            floatx16 acc;
#pragma unroll
            for (int i = 0; i < 16; ++i) acc[i] = 0.f;
#pragma unroll
            for (int ds = 0; ds < 4; ++ds) {
                bf16x8 ak = *(const bf16x8*)&Ks[(t * 32 + l31) * LDT + ds * 16 + half * 8];
                acc = MFMA32x32(ak, aq[ds], acc);
            }
            const unsigned w = (unsigned)(m64 >> (t * 32 + half * 8));
#pragma unroll
            for (int r = 0; r < 16; ++r) {
                float e = fexp2(acc[r]);                    // v_exp_f32
                int sx = sbfe1(w, (r >> 3) * 16 + (r & 7)); // 0 or -1
                float p = __uint_as_float(__float_as_uint(e) & (unsigned)sx);
                rsum += p;
                pB[t * 2 + (r >> 3)][r & 7] = (bf16)p;
            }
        }

        // ---- O^T += V^T · P^T : A = Vt rows (natural), B = pB k-slices ----
#pragma unroll
        for (int dt = 0; dt < 2; ++dt)
#pragma unroll
            for (int s_ = 0; s_ < 4; ++s_) {
                bf16x8 av = *(const bf16x8*)&Vt[(dt * 32 + l31) * LDT + s_ * 16 + half * 8];
                O[dt] = MFMA32x32(av, pB[s_], O[dt]);
            }
    }

    // ---- reduce row sums: lanes l and l+32 share q = l31, disjoint k halves ----
    rsum += __shfl_xor(rsum, 32, 64);
    const float inv = (rsum > 0.f) ? (1.f / rsum) : 0.f;

    // ---- epilogue: O^T[d][q] -> heads[b][q][h][d]; d = dt*32 + g*8 + half*4 + j ----
    bf16* hrow = heads + ((size_t)((b * S + qw + l31) * H + h)) * Dh;
#pragma unroll
    for (int dt = 0; dt < 2; ++dt) {
#pragma unroll
        for (int g = 0; g < 4; ++g) {
            bf16x4 h4;
#pragma unroll
            for (int j = 0; j < 4; ++j) h4[j] = (bf16)(O[dt][g * 4 + j] * inv);
            *(bf16x4*)&hrow[dt * 32 + g * 8 + half * 4] = h4;
        }
    }
}

// Projection: heads (8192x1024) @ Wt^T, 128x128 block tile, 4 waves x 64x64.
__global__ __launch_bounds__(256)
void proj_kernel(const bf16* __restrict__ A, const bf16* __restrict__ Wt,
                 float* __restrict__ out)
{
    __shared__ bf16 As[128 * LDT];
    __shared__ bf16 Ws[128 * LDT];

    const int tid  = threadIdx.x;
    const int lane = tid & 63;
    const int wave = tid >> 6;
    const int l15  = lane & 15;
    const int quad = lane >> 4;

    const int nb = blockIdx.x & 7;
    const int mb = blockIdx.x >> 3;
    const int mbase = mb * 128, nbase = nb * 128;
    const int wm = (wave & 1) * 64, wn = (wave >> 1) * 64;

    const int pr = tid >> 1, pc = (tid & 1) * 32;

    floatx4 O[4][4];
#pragma unroll
    for (int mt = 0; mt < 4; ++mt)
#pragma unroll
        for (int nt = 0; nt < 4; ++nt) O[mt][nt] = floatx4{0.f, 0.f, 0.f, 0.f};

    for (int kt = 0; kt < 16; ++kt) {
        const int kb = kt * 64;
        const bf16* asrc = A  + (size_t)(mbase + pr) * D + kb + pc;
        const bf16* wsrc = Wt + (size_t)(nbase + pr) * D + kb + pc;
        ushort8 a0 = *(const ushort8*)asrc;
        ushort8 a1 = *(const ushort8*)(asrc + 8);
        ushort8 a2 = *(const ushort8*)(asrc + 16);
        ushort8 a3 = *(const ushort8*)(asrc + 24);
        ushort8 w0 = *(const ushort8*)wsrc;
        ushort8 w1 = *(const ushort8*)(wsrc + 8);
        ushort8 w2 = *(const ushort8*)(wsrc + 16);
        ushort8 w3 = *(const ushort8*)(wsrc + 24);

        __syncthreads();
        *(ushort8*)&As[pr * LDT + pc]      = a0;
        *(ushort8*)&As[pr * LDT + pc + 8]  = a1;
        *(ushort8*)&As[pr * LDT + pc + 16] = a2;
        *(ushort8*)&As[pr * LDT + pc + 24] = a3;
        *(ushort8*)&Ws[pr * LDT + pc]      = w0;
        *(ushort8*)&Ws[pr * LDT + pc + 8]  = w1;
        *(ushort8*)&Ws[pr * LDT + pc + 16] = w2;
        *(ushort8*)&Ws[pr * LDT + pc + 24] = w3;
        __syncthreads();

        bf16x8 fa[4][2];
#pragma unroll
        for (int mt = 0; mt < 4; ++mt) {
            fa[mt][0] = *(const bf16x8*)&As[(wm + mt * 16 + l15) * LDT + quad * 8];
            fa[mt][1] = *(const bf16x8*)&As[(wm + mt * 16 + l15) * LDT + quad * 8 + 32];
        }
#pragma unroll
        for (int nt = 0; nt < 4; ++nt) {
            bf16x8 fb0 = *(const bf16x8*)&Ws[(wn + nt * 16 + l15) * LDT + quad * 8];
            bf16x8 fb1 = *(const bf16x8*)&Ws[(wn + nt * 16 + l15) * LDT + quad * 8 + 32];
#pragma unroll
            for (int mt = 0; mt < 4; ++mt) {
                O[mt][nt] = MFMA32(fa[mt][0], fb0, O[mt][nt]);
                O[mt][nt] = MFMA32(fa[mt][1], fb1, O[mt][nt]);
            }
        }
    }

#pragma unroll
    for (int mt = 0; mt < 4; ++mt) {
#pragma unroll
        for (int nt = 0; nt < 4; ++nt) {
#pragma unroll
            for (int reg = 0; reg < 4; ++reg) {
                const int m = mbase + wm + mt * 16 + quad * 4 + reg;
                const int n = nbase + wn + nt * 16 + l15;
                out[(size_t)m * D + n] = O[mt][nt][reg];
            }
        }
    }
}

extern "C" void kernel_launch(void* const* d_in, const int* in_sizes, int n_in,
                              void* d_out, int out_size, void* d_ws, size_t ws_size,
                              hipStream_t stream)
{
    const float* pre_q = (const float*)d_in[0];
    const float* pre_v = (const float*)d_in[1];
    const float* pre_k = (const float*)d_in[2];
    const int*   mask  = (const int*)d_in[3];
    const float* Wg    = (const float*)d_in[4];
    float* out = (float*)d_out;

    bf16* Kc    = (bf16*)d_ws;
    bf16* Vt    = Kc + QN;
    bf16* Wt    = Vt + QN;
    bf16* heads = Wt + WN;
    u64*  MB    = (u64*)(heads + QN);

    prep_kernel<<<10496, 256, 0, stream>>>(pre_k, pre_v, Wg, mask, Kc, Vt, Wt, MB);
    attn_kernel<<<1024, 256, 0, stream>>>(pre_q, Kc, Vt, MB, heads);
    proj_kernel<<<512, 256, 0, stream>>>(heads, Wt, out);
}